// Round 2
// baseline (312.817 us; speedup 1.0000x reference)
//
#include <hip/hip_runtime.h>

#define NN 50000
#define NE 800000
#define FDIM 64

// ---------------------------------------------------------------- degree ----
__global__ void k_degree(const int* __restrict__ col,
                         int* __restrict__ deg, int E) {
    int i = blockIdx.x * blockDim.x + threadIdx.x;
    int stride = gridDim.x * blockDim.x;
    for (; i < E; i += stride) {
        atomicAdd(&deg[col[i]], 1);
    }
}

// ------------------------------------------------------- y = x @ W^T --------
// wave-per-row, lane = out feature. W staged in LDS with +1 pad (65) so
// lane-varying row access hits distinct banks.
__global__ void k_gemm(const float* __restrict__ x, const float* __restrict__ W,
                       float* __restrict__ y, int n) {
    __shared__ float Wl[FDIM * (FDIM + 1)];
    for (int i = threadIdx.x; i < FDIM * FDIM; i += blockDim.x) {
        int o = i / FDIM, k = i % FDIM;
        Wl[o * (FDIM + 1) + k] = W[i];
    }
    __syncthreads();

    int lane  = threadIdx.x & 63;
    int wave  = (blockIdx.x * blockDim.x + threadIdx.x) >> 6;
    int nwave = (gridDim.x * blockDim.x) >> 6;

    for (int r = wave; r < n; r += nwave) {
        float xv = x[r * FDIM + lane];
        float acc = 0.f;
#pragma unroll
        for (int k = 0; k < FDIM; ++k) {
            float a = __shfl(xv, k, 64);
            acc += a * Wl[lane * (FDIM + 1) + k];
        }
        y[r * FDIM + lane] = acc;
    }
}

// ------------------------------------------------- out[n][f] = bias[f] ------
__global__ void k_init_bias(float* __restrict__ out, const float* __restrict__ b,
                            int total) {
    int i = blockIdx.x * blockDim.x + threadIdx.x;
    int stride = gridDim.x * blockDim.x;
    for (; i < total; i += stride) {
        out[i] = b[i & (FDIM - 1)];
    }
}

// -------------------------------------------- scatter: out[col] += v*y[row] -
// one wave per edge, lane = feature
__global__ void k_scatter(const int* __restrict__ rowi,
                          const int* __restrict__ coli,
                          const int* __restrict__ deg,
                          const float* __restrict__ y,
                          float* __restrict__ out, int E) {
    int lane  = threadIdx.x & 63;
    int wave  = (blockIdx.x * blockDim.x + threadIdx.x) >> 6;
    int nwave = (gridDim.x * blockDim.x) >> 6;

    for (int e = wave; e < E; e += nwave) {
        int r = rowi[e];
        int c = coli[e];
        int dr = deg[r];
        if (dr == 0) continue;            // d_out == 0 -> value = 0
        int dc = deg[c];                  // >= 1 by construction
        float v = rsqrtf((float)dr) * rsqrtf((float)dc);
        atomicAdd(&out[c * FDIM + lane], v * y[r * FDIM + lane]);
    }
}

// ---------------------------------------------------------------------------
extern "C" void kernel_launch(void* const* d_in, const int* in_sizes, int n_in,
                              void* d_out, int out_size, void* d_ws, size_t ws_size,
                              hipStream_t stream) {
    const float* x    = (const float*)d_in[0];
    // d_in[1] = x0 (unused: use_init=False)
    const int*   ei   = (const int*)d_in[2];   // harness stores integers as int32
    const float* W_w  = (const float*)d_in[3];
    const float* W_b  = (const float*)d_in[4];
    float*       out  = (float*)d_out;

    const int* rowi = ei;          // edge_index[0]
    const int* coli = ei + NE;     // edge_index[1]

    // workspace layout: deg (N ints) | y (N*64 floats)
    int*   deg = (int*)d_ws;
    size_t deg_bytes = ((size_t)NN * sizeof(int) + 255) & ~(size_t)255;
    float* y   = (float*)((char*)d_ws + deg_bytes);

    hipMemsetAsync(deg, 0, (size_t)NN * sizeof(int), stream);

    // degree
    k_degree<<<1024, 256, 0, stream>>>(coli, deg, NE);

    // y = x @ W^T   (50000 rows, 4 waves/block)
    k_gemm<<<2048, 256, 0, stream>>>(x, W_w, y, NN);

    // out = bias
    k_init_bias<<<2048, 256, 0, stream>>>(out, W_b, NN * FDIM);

    // scatter-accumulate: one wave per edge
    k_scatter<<<200000, 256, 0, stream>>>(rowi, coli, deg, y, out, NE);
}